// Round 3
// baseline (84.442 us; speedup 1.0000x reference)
//
#include <hip/hip_runtime.h>
#include <math.h>

namespace {
constexpr int   T_STEPS = 400;
constexpr int   HALF    = 200;           // T/2 — scan covers t = 1..200
constexpr int   NPIX    = 250 * 400;     // 100000
constexpr int   CHUNK   = 32;            // timesteps per load chunk
constexpr int   BLOCK   = 64;            // one wave per block: no LDS, no barriers
constexpr int   NBLK    = (NPIX + BLOCK - 1) / BLOCK;           // 1563
constexpr int   NORM_BLOCK = 256;
constexpr int   NORM_NBLK  = (NPIX + NORM_BLOCK - 1) / NORM_BLOCK;
constexpr float U0 = 0.15f;
}

// R1-verbatim exact math: n recurrence steps with interval d.
__device__ __forceinline__ void apply_segment(float& R, float& u, int d, int n) {
  const float dd = (float)d;
  const float eD = expf(-dd);              // exp(-isi / D), D = 1
  const float eF = expf(-(dd / 10.0f));    // exp(-isi / F), F = 10
  for (int k = 0; k < n; ++k) {
    const float Rn = 1.0f - (1.0f - R * (1.0f - u)) * eD;
    const float un = U0 + (u + 0.15f * (1.0f - u) - U0) * eF;
    R = Rn; u = un;
  }
}

__device__ __forceinline__ void proc_mask(unsigned mask, int t0, int& prev,
                                          float& R, float& u, bool& done) {
  if (done) return;
  while (mask) {
    const int i = __builtin_ctz(mask);
    mask &= mask - 1u;
    const int t = t0 + i;
    if (prev >= 0) {
      const int d = t - prev;
      // t <= HALF: segment (prev, t], endpoint updates only when isi==1
      // t >  HALF: segment clipped to (prev, HALF]
      const int n = (t <= HALF) ? ((d == 1) ? 1 : (d - 1)) : (HALF - prev);
      apply_segment(R, u, d, n);
    }
    prev = t;
    if (t >= HALF) { done = true; return; }
  }
}

__global__ __launch_bounds__(BLOCK) void stp_compute(
    const float* __restrict__ spikes, float* __restrict__ img,
    float* __restrict__ pmin, float* __restrict__ pmax) {
  const int  p      = blockIdx.x * BLOCK + threadIdx.x;
  const bool active = (p < NPIX);
  const float* __restrict__ sp = spikes + (active ? p : (NPIX - 1));

  bool  done = !active;
  int   prev = -1;
  float R = 1.0f, u = U0;

  auto loadc = [&](float (&buf)[CHUNK], int c) {
#pragma unroll
    for (int i = 0; i < CHUNK; ++i) {
      const unsigned idx = (unsigned)(c * CHUNK + i) * (unsigned)NPIX;
      buf[i] = sp[idx];
    }
  };
  auto maskof = [&](const float (&buf)[CHUNK]) -> unsigned {
    unsigned m = 0u;
#pragma unroll
    for (int i = 0; i < CHUNK; ++i) m |= (buf[i] > 0.0f) ? (1u << i) : 0u;
    return m;
  };

  // Software-pipelined: chunk c+1's 32 loads in flight while chunk c is
  // processed. Chunks 0..6 cover t in [0,223]; P(lane not done by then)
  // ~ 2^-24 per pixel.
  float va[CHUNK], vb[CHUNK];
  loadc(va, 0);
  loadc(vb, 1);
  unsigned m;
  m = maskof(va); loadc(va, 2); proc_mask(m, 0 * CHUNK, prev, R, u, done);
  m = maskof(vb); loadc(vb, 3); proc_mask(m, 1 * CHUNK, prev, R, u, done);
  m = maskof(va); loadc(va, 4); proc_mask(m, 2 * CHUNK, prev, R, u, done);
  m = maskof(vb); loadc(vb, 5); proc_mask(m, 3 * CHUNK, prev, R, u, done);
  m = maskof(va); loadc(va, 6); proc_mask(m, 4 * CHUNK, prev, R, u, done);
  m = maskof(vb);               proc_mask(m, 5 * CHUNK, prev, R, u, done);
  m = maskof(va);               proc_mask(m, 6 * CHUNK, prev, R, u, done);

  // Rare tail (exact even if a lane never spikes again: isi=inf -> no update).
  for (int c = 7; c <= (T_STEPS - 1) / CHUNK; ++c) {
    if (__all((int)done)) break;
    unsigned mt = 0u;
#pragma unroll
    for (int i = 0; i < CHUNK; ++i) {
      const int t = c * CHUNK + i;
      float v = 0.0f;
      if (t < T_STEPS) v = sp[(unsigned)t * (unsigned)NPIX];
      mt |= (v > 0.0f) ? (1u << i) : 0u;
    }
    proc_mask(mt, c * CHUNK, prev, R, u, done);
  }

  float val = 0.0f;
  if (active) {
    const float lu = logf((u - U0) / (10.0f - U0 + u * 0.85f));
    const float lR = logf((1.0f - R) / (1.0f - R * (1.0f - u)));
    val = (-1.0f / (10.0f * lu)) + (-1.0f / lR);
    img[p] = val;
  }

  // single-wave block: shuffle-only min/max reduction
  float vmin = active ? val : INFINITY;
  float vmax = active ? val : -INFINITY;
#pragma unroll
  for (int off = 32; off > 0; off >>= 1) {
    vmin = fminf(vmin, __shfl_down(vmin, off, 64));
    vmax = fmaxf(vmax, __shfl_down(vmax, off, 64));
  }
  if (threadIdx.x == 0) {
    pmin[blockIdx.x] = vmin;
    pmax[blockIdx.x] = vmax;
  }
}

__global__ __launch_bounds__(512) void reduce_minmax(
    const float* __restrict__ pmin, const float* __restrict__ pmax,
    float* __restrict__ mm) {
  float vmin = INFINITY, vmax = -INFINITY;
  for (int i = threadIdx.x; i < NBLK; i += 512) {
    vmin = fminf(vmin, pmin[i]);
    vmax = fmaxf(vmax, pmax[i]);
  }
#pragma unroll
  for (int off = 32; off > 0; off >>= 1) {
    vmin = fminf(vmin, __shfl_down(vmin, off, 64));
    vmax = fmaxf(vmax, __shfl_down(vmax, off, 64));
  }
  __shared__ float smin[8], smax[8];
  const int lane = threadIdx.x & 63, wid = threadIdx.x >> 6;
  if (lane == 0) { smin[wid] = vmin; smax[wid] = vmax; }
  __syncthreads();
  if (threadIdx.x == 0) {
    float mn = smin[0], mx = smax[0];
#pragma unroll
    for (int i = 1; i < 8; ++i) {
      mn = fminf(mn, smin[i]);
      mx = fmaxf(mx, smax[i]);
    }
    mm[0] = mn;
    mm[1] = mx;
  }
}

__global__ __launch_bounds__(NORM_BLOCK) void normalize_k(
    float* __restrict__ img, const float* __restrict__ mm) {
  const int p = blockIdx.x * NORM_BLOCK + threadIdx.x;
  if (p < NPIX) {
    const float mn = mm[0], mx = mm[1];
    const float v  = img[p];
    img[p] = (mx != mn) ? (v - mn) / (mx - mn) : v;
  }
}

extern "C" void kernel_launch(void* const* d_in, const int* in_sizes, int n_in,
                              void* d_out, int out_size, void* d_ws, size_t ws_size,
                              hipStream_t stream) {
  const float* spikes = (const float*)d_in[0];
  float* out  = (float*)d_out;
  float* ws   = (float*)d_ws;
  float* mm   = ws;                    // [0]=min, [1]=max
  float* pmin = ws + 2;                // NBLK partial mins
  float* pmax = ws + 2 + NBLK;         // NBLK partial maxes

  hipLaunchKernelGGL(stp_compute, dim3(NBLK), dim3(BLOCK), 0, stream,
                     spikes, out, pmin, pmax);
  hipLaunchKernelGGL(reduce_minmax, dim3(1), dim3(512), 0, stream,
                     pmin, pmax, mm);
  hipLaunchKernelGGL(normalize_k, dim3(NORM_NBLK), dim3(NORM_BLOCK), 0, stream,
                     out, mm);
}